// Round 2
// baseline (2569.843 us; speedup 1.0000x reference)
//
#include <hip/hip_runtime.h>

constexpr int NROW  = 16384;   // B*T
constexpr int DIM   = 512;
constexpr int KCODE = 8192;

constexpr int TM  = 32;    // rows per block
constexpr int TC  = 128;   // codes per tile
constexpr int DCH = 32;    // depth chunk

// d_out offsets (in floats)
constexpr size_t Q_OFF = 0;          // quantized_st [16,1024,512]
constexpr size_t T_OFF = 8388608;    // targets [16,1024]
constexpr size_t L_OFF = 8404992;    // extra_losses scalar
constexpr size_t E_OFF = 8404993;    // new_embeddings [8192,512]
constexpr size_t C_OFF = 12599297;   // new_cs [8192]
constexpr size_t W_OFF = 12607489;   // new_w [8192,512]

// ws offsets (bytes)
constexpr size_t WS_IDX    = 0;        // int[NROW]
constexpr size_t WS_CSIZE  = 65536;    // float[KCODE]
constexpr size_t WS_COMMIT = 98304;    // float
constexpr size_t WS_CSSUM  = 98308;    // float
constexpr size_t WS_XNORM  = 131072;   // float[NROW]
constexpr size_t WS_ENORM  = 196608;   // float[KCODE]
constexpr size_t WS_ESUM   = 262144;   // float[KCODE*DIM]
constexpr size_t WS_NEEDED = WS_ESUM + (size_t)KCODE * DIM * 4;

// ---------------- kernel 1: row sum-of-squares, numpy pairwise order --------
// Replicates np.sum(a*a, axis=1) for contiguous fp32 rows of length 512:
// pairwise_sum recursion: (B0+B1)+(B2+B3) over 128-blocks; each block uses 8
// sequential accumulators r_j = sum_t p[8t+j], combined
// ((r0+r1)+(r2+r3))+((r4+r5)+(r6+r7)).  Products rounded (NO fma).
__global__ void rownorm_kernel(const float* __restrict__ src, float* __restrict__ dst) {
    #pragma clang fp contract(off)
    __shared__ float s[4][DIM];
    __shared__ float rr[4][32];
    const int wave = threadIdx.x >> 6, lane = threadIdx.x & 63;
    const int row = blockIdx.x * 4 + wave;
    const float4* p = (const float4*)(src + (size_t)row * DIM);
    float4 v0 = p[lane];
    float4 v1 = p[lane + 64];
    *(float4*)&s[wave][lane * 4] = v0;
    *(float4*)&s[wave][(lane + 64) * 4] = v1;
    __syncthreads();
    if (lane < 32) {
        const int b = lane >> 3, j = lane & 7;
        const float* q = &s[wave][b * 128 + j];
        float x = q[0];
        float r = x * x;                       // rounded mul
        for (int t = 1; t < 16; ++t) {
            float y = q[8 * t];
            float py = y * y;                  // rounded mul
            r = r + py;                        // rounded add (no contraction)
        }
        rr[wave][lane] = r;
    }
    __syncthreads();
    if (lane == 0) {
        const float* R = rr[wave];
        float B0 = ((R[0] + R[1]) + (R[2] + R[3])) + ((R[4] + R[5]) + (R[6] + R[7]));
        float B1 = ((R[8] + R[9]) + (R[10] + R[11])) + ((R[12] + R[13]) + (R[14] + R[15]));
        float B2 = ((R[16] + R[17]) + (R[18] + R[19])) + ((R[20] + R[21]) + (R[22] + R[23]));
        float B3 = ((R[24] + R[25]) + (R[26] + R[27])) + ((R[28] + R[29]) + (R[30] + R[31]));
        dst[row] = (B0 + B1) + (B2 + B3);
    }
}

// ---------------- kernel 2: argmin emulating numpy fp32 d2 ------------------
// d2_j = fl( fl(xnorm - 2*dot_j) + enorm_j ), dot_j = sequential k-ascending
// fp32 FMA chain (matches BLAS microkernel accumulation to ~1 ulp of dot).
__launch_bounds__(256, 2)
__global__ void argmin_kernel(const float* __restrict__ feat,
                              const float* __restrict__ emb,
                              const float* __restrict__ xnorm,
                              const float* __restrict__ enorm,
                              int* __restrict__ gidx,
                              float* __restrict__ targets) {
    __shared__ float As[DCH][TM + 4];    // [32][36]
    __shared__ float Bs[DCH][TC + 4];    // [32][132]

    const int tid = threadIdx.x;
    const int tx = tid & 31, ty = tid >> 5;
    const int row0 = blockIdx.x * TM;
    const int r0 = ty * 4, c0 = tx * 4;

    float xn[4];
    #pragma unroll
    for (int i = 0; i < 4; ++i) xn[i] = xnorm[row0 + r0 + i];

    float bestv[4] = {3.4e38f, 3.4e38f, 3.4e38f, 3.4e38f};
    int   besti[4] = {0, 0, 0, 0};

    for (int ct = 0; ct < KCODE; ct += TC) {
        float acc[4][4] = {};
        for (int d0 = 0; d0 < DIM; d0 += DCH) {
            {   // stage A: 32 rows x 32 depth, transposed
                int r = tid >> 3, j4 = (tid & 7) * 4;
                float4 v = *(const float4*)&feat[(size_t)(row0 + r) * DIM + d0 + j4];
                As[j4 + 0][r] = v.x; As[j4 + 1][r] = v.y;
                As[j4 + 2][r] = v.z; As[j4 + 3][r] = v.w;
            }
            #pragma unroll
            for (int p = 0; p < 4; ++p) {   // stage B: 128 codes x 32 depth
                int q = p * 256 + tid;
                int c = q >> 3, j4 = (q & 7) * 4;
                float4 v = *(const float4*)&emb[(size_t)(ct + c) * DIM + d0 + j4];
                Bs[j4 + 0][c] = v.x; Bs[j4 + 1][c] = v.y;
                Bs[j4 + 2][c] = v.z; Bs[j4 + 3][c] = v.w;
            }
            __syncthreads();
            #pragma unroll
            for (int kk = 0; kk < DCH; ++kk) {
                float4 av = *(const float4*)&As[kk][r0];
                float4 bv = *(const float4*)&Bs[kk][c0];
                float a[4] = {av.x, av.y, av.z, av.w};
                float b[4] = {bv.x, bv.y, bv.z, bv.w};
                #pragma unroll
                for (int i = 0; i < 4; ++i)
                    #pragma unroll
                    for (int u = 0; u < 4; ++u)
                        acc[i][u] = fmaf(a[i], b[u], acc[i][u]);   // k-ascending chain
            }
            __syncthreads();
        }
        #pragma unroll
        for (int u = 0; u < 4; ++u) {
            int code = ct + c0 + u;
            float en = enorm[code];
            #pragma unroll
            for (int i = 0; i < 4; ++i) {
                // fl(xnorm - 2*dot): 2*acc is exact, so fused form == numpy's
                float t2 = fmaf(-2.0f, acc[i][u], xn[i]);
                float s = t2 + en;                       // rounded add
                if (s < bestv[i]) { bestv[i] = s; besti[i] = code; }  // first-index tie-break
            }
        }
    }

    // cross-thread reduction per row, lowest-index on exact tie
    float* sval = &Bs[0][0];
    int*   sidx = (int*)&As[0][0];
    #pragma unroll
    for (int i = 0; i < 4; ++i) {
        sval[(r0 + i) * 33 + tx] = bestv[i];
        sidx[(r0 + i) * 33 + tx] = besti[i];
    }
    __syncthreads();
    if (tid < TM) {
        float bv = sval[tid * 33]; int bi = sidx[tid * 33];
        for (int t = 1; t < 32; ++t) {
            float v = sval[tid * 33 + t]; int ii = sidx[tid * 33 + t];
            if (v < bv || (v == bv && ii < bi)) { bv = v; bi = ii; }
        }
        gidx[row0 + tid] = bi;
        targets[row0 + tid] = (float)bi;
    }
}

// ---------------- kernel 3: gather + commitment + scatter-add ---------------
__global__ void gather_kernel(const float* __restrict__ feat,
                              const float* __restrict__ emb,
                              const int* __restrict__ gidx,
                              float* __restrict__ qout,
                              float* __restrict__ esum,
                              float* __restrict__ csize,
                              float* __restrict__ commit) {
    const int row = blockIdx.x;
    const int code = gidx[row];
    const int d = threadIdx.x * 2;
    float2 f = *(const float2*)&feat[(size_t)row * DIM + d];
    float2 q = *(const float2*)&emb[(size_t)code * DIM + d];
    float2 qst;
    qst.x = f.x + (q.x - f.x);
    qst.y = f.y + (q.y - f.y);
    *(float2*)&qout[(size_t)row * DIM + d] = qst;
    float dx = f.x - qst.x, dy = f.y - qst.y;
    float local = dx * dx + dy * dy;
    #pragma unroll
    for (int off = 32; off; off >>= 1) local += __shfl_down(local, off, 64);
    __shared__ float wsum[4];
    int lane = threadIdx.x & 63, wv = threadIdx.x >> 6;
    if (lane == 0) wsum[wv] = local;
    __syncthreads();
    if (threadIdx.x == 0) {
        atomicAdd(commit, wsum[0] + wsum[1] + wsum[2] + wsum[3]);
        atomicAdd(&csize[code], 1.0f);
    }
    atomicAdd(&esum[(size_t)code * DIM + d], f.x);
    atomicAdd(&esum[(size_t)code * DIM + d + 1], f.y);
}

// ---------------- kernel 4: new_cs + sum(new_cs) + loss ---------------------
__global__ void newcs_kernel(const float* __restrict__ ema_cs,
                             const float* __restrict__ csize,
                             float* __restrict__ out_cs,
                             float* __restrict__ cs_sum,
                             const float* __restrict__ commit,
                             float* __restrict__ out_loss) {
    int i = blockIdx.x * 256 + threadIdx.x;
    float v = 0.99f * ema_cs[i] + 0.01f * csize[i];
    out_cs[i] = v;
    float s = v;
    #pragma unroll
    for (int off = 32; off; off >>= 1) s += __shfl_down(s, off, 64);
    __shared__ float wsum[4];
    int lane = threadIdx.x & 63, wv = threadIdx.x >> 6;
    if (lane == 0) wsum[wv] = s;
    __syncthreads();
    if (threadIdx.x == 0)
        atomicAdd(cs_sum, wsum[0] + wsum[1] + wsum[2] + wsum[3]);
    if (blockIdx.x == 0 && threadIdx.x == 0)
        out_loss[0] = 0.25f * commit[0] / 8388608.0f;
}

// ---------------- kernel 5: new_w + new_embeddings --------------------------
__global__ void final_kernel(const float* __restrict__ ema_w,
                             const float* __restrict__ esum,
                             const float* __restrict__ new_cs,
                             const float* __restrict__ cs_sum,
                             float* __restrict__ out_w,
                             float* __restrict__ out_emb) {
    size_t i4 = ((size_t)blockIdx.x * 256 + threadIdx.x) * 4;
    int k = (int)(i4 >> 9);
    float S = cs_sum[0] + (float)KCODE * 1e-5f;
    float4 es = *(const float4*)&esum[i4];
    float4 ew = *(const float4*)&ema_w[i4];
    float w0 = 0.99f * ew.x + 0.01f * es.x;
    float w1 = 0.99f * ew.y + 0.01f * es.y;
    float w2 = 0.99f * ew.z + 0.01f * es.z;
    float w3 = 0.99f * ew.w + 0.01f * es.w;
    out_w[i4 + 0] = w0; out_w[i4 + 1] = w1; out_w[i4 + 2] = w2; out_w[i4 + 3] = w3;
    float scale = S / (new_cs[k] + 1e-5f);
    out_emb[i4 + 0] = w0 * scale; out_emb[i4 + 1] = w1 * scale;
    out_emb[i4 + 2] = w2 * scale; out_emb[i4 + 3] = w3 * scale;
}

// ---------------------------------------------------------------------------
extern "C" void kernel_launch(void* const* d_in, const int* in_sizes, int n_in,
                              void* d_out, int out_size, void* d_ws, size_t ws_size,
                              hipStream_t stream) {
    const float* feat   = (const float*)d_in[0];
    const float* emb    = (const float*)d_in[1];
    const float* ema_cs = (const float*)d_in[2];
    const float* ema_w  = (const float*)d_in[3];
    float* out = (float*)d_out;
    char* ws = (char*)d_ws;
    if (ws_size < WS_NEEDED) return;

    int*   gidx   = (int*)(ws + WS_IDX);
    float* csize  = (float*)(ws + WS_CSIZE);
    float* commit = (float*)(ws + WS_COMMIT);
    float* cssum  = (float*)(ws + WS_CSSUM);
    float* xnorm  = (float*)(ws + WS_XNORM);
    float* enorm  = (float*)(ws + WS_ENORM);
    float* esum   = (float*)(ws + WS_ESUM);

    hipMemsetAsync(ws + WS_CSIZE, 0, WS_CSSUM + 4 - WS_CSIZE, stream);
    hipMemsetAsync(ws + WS_ESUM, 0, (size_t)KCODE * DIM * 4, stream);

    rownorm_kernel<<<NROW / 4, 256, 0, stream>>>(feat, xnorm);
    rownorm_kernel<<<KCODE / 4, 256, 0, stream>>>(emb, enorm);
    argmin_kernel<<<NROW / TM, 256, 0, stream>>>(feat, emb, xnorm, enorm, gidx, out + T_OFF);
    gather_kernel<<<NROW, 256, 0, stream>>>(feat, emb, gidx, out + Q_OFF, esum, csize, commit);
    newcs_kernel<<<KCODE / 256, 256, 0, stream>>>(ema_cs, csize, out + C_OFF, cssum, commit, out + L_OFF);
    final_kernel<<<KCODE * DIM / 1024, 256, 0, stream>>>(ema_w, esum, out + C_OFF, cssum,
                                                         out + W_OFF, out + E_OFF);
}